// Round 2
// baseline (2439.826 us; speedup 1.0000x reference)
//
#include <hip/hip_runtime.h>

typedef unsigned short u16;
typedef unsigned int u32;
typedef __attribute__((ext_vector_type(8))) short short8;
typedef __attribute__((ext_vector_type(8))) u16 ushort8;
typedef __attribute__((ext_vector_type(4))) float f32x4;

#define T_TOK 2048
#define H_DIM 2048
#define NEXP 64
#define I_DIM 1408
#define SI_DIM 2816
#define BM 256
#define BK 64

__device__ __forceinline__ u16 f2bf(float f) {
    u32 u = __builtin_bit_cast(u32, f);
    u32 r = u + 0x7FFFu + ((u >> 16) & 1u);
    return (u16)(r >> 16);
}

__device__ __forceinline__ ushort8 cvt8(float4 a, float4 b) {
    ushort8 o;
    o[0] = f2bf(a.x); o[1] = f2bf(a.y); o[2] = f2bf(a.z); o[3] = f2bf(a.w);
    o[4] = f2bf(b.x); o[5] = f2bf(b.y); o[6] = f2bf(b.z); o[7] = f2bf(b.w);
    return o;
}

__device__ __forceinline__ f32x4 mfma16(short8 a, short8 b, f32x4 c) {
    return __builtin_amdgcn_mfma_f32_16x16x32_bf16(a, b, c, 0, 0, 0);
}

__device__ __forceinline__ void gld_lds16(const void* g, void* l) {
    __builtin_amdgcn_global_load_lds(
        (const __attribute__((address_space(1))) void*)(g),
        (__attribute__((address_space(3))) void*)(l), 16, 0, 0);
}

// ---------------- x -> bf16 ----------------
__global__ __launch_bounds__(256) void k_cvt(const float* __restrict__ x, u16* __restrict__ xb) {
    int i = (blockIdx.x * 256 + threadIdx.x) * 8;
    float4 v0 = *(const float4*)(x + i);
    float4 v1 = *(const float4*)(x + i + 4);
    *(ushort8*)(xb + i) = cvt8(v0, v1);
}

// ---------------- gating logits: f64 accumulation ----------------
__global__ __launch_bounds__(256) void k_gate_logits(const float* __restrict__ x,
        const float* __restrict__ gw, float* __restrict__ logits) {
    __shared__ float xs[8][65];
    __shared__ float wsh[64][65];
    int tid = threadIdx.x;
    int t0 = blockIdx.x * 8;
    double acc0 = 0.0, acc1 = 0.0;
    int e = tid & 63, tg = tid >> 6; // tg in [0,4)
    for (int k0 = 0; k0 < H_DIM; k0 += 64) {
        #pragma unroll
        for (int s = 0; s < 2; ++s) {
            int idx = s * 256 + tid;
            int r = idx >> 6, k = idx & 63;
            xs[r][k] = x[(size_t)(t0 + r) * H_DIM + k0 + k];
        }
        #pragma unroll
        for (int s = 0; s < 16; ++s) {
            int idx = s * 256 + tid;
            int r = idx >> 6, k = idx & 63;
            wsh[r][k] = gw[(size_t)r * H_DIM + k0 + k];
        }
        __syncthreads();
        #pragma unroll 8
        for (int k = 0; k < 64; ++k) {
            double wv = (double)wsh[e][k];
            acc0 += (double)xs[tg][k] * wv;
            acc1 += (double)xs[tg + 4][k] * wv;
        }
        __syncthreads();
    }
    logits[(size_t)(t0 + tg) * NEXP + e] = (float)acc0;
    logits[(size_t)(t0 + tg + 4) * NEXP + e] = (float)acc1;
}

// ---------------- per-token group-restricted top-k ----------------
__global__ __launch_bounds__(256) void k_topk(const float* __restrict__ logits,
        const float* __restrict__ ebias, int* __restrict__ topk_idx,
        float* __restrict__ topk_w, int* __restrict__ counts) {
    __shared__ float bsh[64];
    if (threadIdx.x < 64) bsh[threadIdx.x] = ebias[threadIdx.x];
    __syncthreads();
    int t = blockIdx.x * 256 + threadIdx.x;
    float sc[64];
    #pragma unroll
    for (int e2 = 0; e2 < 64; ++e2) {
        float lg = logits[(size_t)t * 64 + e2];
        sc[e2] = 1.0f / (1.0f + expf(-lg));
    }
    float gsc[8];
    #pragma unroll
    for (int g = 0; g < 8; ++g) {
        float m1 = -1e30f, m2 = -1e30f;
        #pragma unroll
        for (int j = 0; j < 8; ++j) {
            float v = sc[g * 8 + j] + bsh[g * 8 + j];
            if (v > m1) { m2 = m1; m1 = v; }
            else if (v > m2) { m2 = v; }
        }
        gsc[g] = m1 + m2;
    }
    u32 gmask = 0;
    #pragma unroll
    for (int it = 0; it < 4; ++it) {
        float best = -1e30f; int bi = 0;
        #pragma unroll
        for (int g = 0; g < 8; ++g) {
            bool ok = !((gmask >> g) & 1u);
            if (ok && gsc[g] > best) { best = gsc[g]; bi = g; }
        }
        gmask |= 1u << bi;
    }
    unsigned long long avail = 0ull;
    #pragma unroll
    for (int g = 0; g < 8; ++g)
        if ((gmask >> g) & 1u) avail |= (0xFFull << (g * 8));
    float wsum = 0.f;
    int idx[8]; float wv[8];
    #pragma unroll
    for (int it = 0; it < 8; ++it) {
        float best = -1e30f, bw = 0.f; int bi = 0;
        #pragma unroll
        for (int e2 = 0; e2 < 64; ++e2) {
            bool ok = (avail >> e2) & 1ull;
            float v = sc[e2] + bsh[e2];
            if (ok && v > best) { best = v; bi = e2; bw = sc[e2]; }
        }
        avail &= ~(1ull << bi);
        idx[it] = bi; wv[it] = bw; wsum += bw;
    }
    float scale = 2.5f / (wsum + 1e-20f);
    #pragma unroll
    for (int it = 0; it < 8; ++it) {
        topk_idx[t * 8 + it] = idx[it];
        topk_w[t * 8 + it] = wv[it] * scale;
        atomicAdd(&counts[idx[it]], 1);
    }
}

// ---------------- prefix sum over 64 counts ----------------
__global__ void k_prefix(const int* __restrict__ counts, int* __restrict__ offsets) {
    if (threadIdx.x == 0) {
        int run = 0;
        for (int e = 0; e < 64; ++e) { offsets[e] = run; run += counts[e]; }
        offsets[64] = run;
    }
}

// ---------------- scatter (t,k) -> per-expert lists ----------------
__global__ __launch_bounds__(256) void k_scatter(const int* __restrict__ topk_idx,
        const float* __restrict__ topk_w, const int* __restrict__ offsets,
        int* __restrict__ fill, int* __restrict__ tok_list, float* __restrict__ w_list) {
    int gid = blockIdx.x * 256 + threadIdx.x;
    int t = gid >> 3;
    int e = topk_idx[gid];
    int pos = offsets[e] + atomicAdd(&fill[e], 1);
    tok_list[pos] = t;
    w_list[pos] = topk_w[gid];
}

// ---------------- fused gate+up+silu*mul grouped GEMM ----------------
// tile: 256 tokens x 64 I-rows, BK=64; 8 waves each 32m x 64n x {g,u}
// A via global_load_lds (source-preswizzled, dbuf), B reg-staged 1 step ahead.
__global__ __launch_bounds__(512, 4) void k_gateup(
        const u16* __restrict__ xb,
        const float* __restrict__ gate_base, const float* __restrict__ up_base,
        const int* __restrict__ offsets, const int* __restrict__ tok_list,
        u16* __restrict__ inter, int Irows) {
    int i0 = blockIdx.x * 64;
    int m0 = blockIdx.y * BM;
    int e = blockIdx.z;
    int seg, n;
    if (offsets) { seg = offsets[e]; n = offsets[e + 1] - seg; }
    else { seg = 0; n = T_TOK; }
    if (m0 >= n) return;

    const float* Bg = gate_base + (size_t)e * Irows * H_DIM;
    const float* Bu = up_base + (size_t)e * Irows * H_DIM;

    __shared__ u16 As[2][BM * BK];   // 2 x 32KB, linear (source-preswizzled)
    __shared__ u16 Bsg[64 * BK];     // 8KB, xor-swizzled
    __shared__ u16 Bsu[64 * BK];     // 8KB

    int tid = threadIdx.x;
    int w = tid >> 6, lane = tid & 63;

    // A sources: 4 gld_lds calls/thread; call s covers LDS rows [(s*8+w)*8, +8)
    const u16* asrc[4];
    #pragma unroll
    for (int s = 0; s < 4; ++s) {
        int row = (s * 8 + w) * 8 + (lane >> 3);
        int cb = lane & 7;
        int p = m0 + row; if (p >= n) p = n - 1;
        int tok = tok_list ? tok_list[seg + p] : p;
        asrc[s] = xb + (size_t)tok * H_DIM + ((cb ^ (row & 7)) * 8);
    }
    // B staging: thread -> (row=tid>>3, cb=tid&7), one 16B slot per matrix
    int br = tid >> 3, bcb = tid & 7;
    const float* bgsrc = Bg + (size_t)(i0 + br) * H_DIM + bcb * 8;
    const float* busrc = Bu + (size_t)(i0 + br) * H_DIM + bcb * 8;
    int bdst = br * BK + ((bcb ^ (br & 7)) * 8);

    f32x4 zero; zero[0] = 0.f; zero[1] = 0.f; zero[2] = 0.f; zero[3] = 0.f;
    f32x4 accg[2][4], accu[2][4];
    #pragma unroll
    for (int a = 0; a < 2; ++a)
        #pragma unroll
        for (int b = 0; b < 4; ++b) { accg[a][b] = zero; accu[a][b] = zero; }

    auto issueA = [&](int k0, int pb) {
        #pragma unroll
        for (int s = 0; s < 4; ++s)
            gld_lds16(asrc[s] + k0, (u16*)As[pb] + (s * 8 + w) * 512);
    };
    auto mmaStep = [&](int pb) {
        #pragma unroll
        for (int ks = 0; ks < 2; ++ks) {
            short8 a[2];
            #pragma unroll
            for (int fm = 0; fm < 2; ++fm) {
                int row = w * 32 + fm * 16 + (lane & 15);
                int cb = ks * 4 + (lane >> 4);
                a[fm] = *(const short8*)((const u16*)As[pb] + row * BK + ((cb ^ (row & 7)) * 8));
            }
            #pragma unroll
            for (int fn = 0; fn < 4; ++fn) {
                int brow = fn * 16 + (lane & 15);
                int cb = ks * 4 + (lane >> 4);
                int boff = brow * BK + ((cb ^ (brow & 7)) * 8);
                short8 bg = *(const short8*)(&Bsg[boff]);
                short8 bu = *(const short8*)(&Bsu[boff]);
                accg[0][fn] = mfma16(a[0], bg, accg[0][fn]);
                accg[1][fn] = mfma16(a[1], bg, accg[1][fn]);
                accu[0][fn] = mfma16(a[0], bu, accu[0][fn]);
                accu[1][fn] = mfma16(a[1], bu, accu[1][fn]);
            }
        }
    };

    const int NK = H_DIM / BK; // 32 (even)
    // prologue
    issueA(0, 0);
    float4 gA0 = *(const float4*)bgsrc, gA1 = *(const float4*)(bgsrc + 4);
    float4 uA0 = *(const float4*)busrc, uA1 = *(const float4*)(busrc + 4);
    float4 gB0, gB1, uB0, uB1;

    for (int ki = 0; ki < NK; ki += 2) {
        // even step (buffer 0, regs A)
        *(ushort8*)(&Bsg[bdst]) = cvt8(gA0, gA1);
        *(ushort8*)(&Bsu[bdst]) = cvt8(uA0, uA1);
        if (ki + 1 < NK) {
            int k1 = (ki + 1) * BK;
            issueA(k1, 1);
            gB0 = *(const float4*)(bgsrc + k1); gB1 = *(const float4*)(bgsrc + k1 + 4);
            uB0 = *(const float4*)(busrc + k1); uB1 = *(const float4*)(busrc + k1 + 4);
        }
        __syncthreads();
        mmaStep(0);
        __syncthreads();
        // odd step (buffer 1, regs B)
        if (ki + 1 < NK) {
            *(ushort8*)(&Bsg[bdst]) = cvt8(gB0, gB1);
            *(ushort8*)(&Bsu[bdst]) = cvt8(uB0, uB1);
            if (ki + 2 < NK) {
                int k2 = (ki + 2) * BK;
                issueA(k2, 0);
                gA0 = *(const float4*)(bgsrc + k2); gA1 = *(const float4*)(bgsrc + k2 + 4);
                uA0 = *(const float4*)(busrc + k2); uA1 = *(const float4*)(busrc + k2 + 4);
            }
            __syncthreads();
            mmaStep(1);
            __syncthreads();
        }
    }

    int r0 = (lane >> 4) * 4, cc = lane & 15;
    #pragma unroll
    for (int fm = 0; fm < 2; ++fm) {
        #pragma unroll
        for (int r = 0; r < 4; ++r) {
            int p = m0 + w * 32 + fm * 16 + r0 + r;
            if (p < n) {
                size_t rowb = (size_t)(seg + p) * Irows + i0;
                #pragma unroll
                for (int fn = 0; fn < 4; ++fn) {
                    float g = accg[fm][fn][r], u = accu[fm][fn][r];
                    float val = g / (1.0f + expf(-g)) * u;
                    inter[rowb + fn * 16 + cc] = f2bf(val);
                }
            }
        }
    }
}

// ---------------- down-proj grouped GEMM, weighted atomic scatter ----------------
// tile: 256 rows x 128 H; BK=64; 8 waves each 32m x 128n
__global__ __launch_bounds__(512, 4) void k_down(
        const u16* __restrict__ inter, int Kdim,
        const float* __restrict__ down_base,
        const int* __restrict__ offsets, const int* __restrict__ tok_list,
        const float* __restrict__ w_list,
        float* __restrict__ out) {
    int h0 = blockIdx.x * 128;
    int m0 = blockIdx.y * BM;
    int e = blockIdx.z;
    int seg, n;
    if (offsets) { seg = offsets[e]; n = offsets[e + 1] - seg; }
    else { seg = 0; n = T_TOK; }
    if (m0 >= n) return;

    const float* Bd = down_base + (size_t)e * H_DIM * Kdim;

    __shared__ u16 As[2][BM * BK];   // 2 x 32KB
    __shared__ u16 Bs[128 * BK];     // 16KB, xor-swizzled

    int tid = threadIdx.x;
    int w = tid >> 6, lane = tid & 63;

    const u16* asrc[4];
    #pragma unroll
    for (int s = 0; s < 4; ++s) {
        int row = (s * 8 + w) * 8 + (lane >> 3);
        int cb = lane & 7;
        int p = m0 + row; if (p >= n) p = n - 1;
        asrc[s] = inter + (size_t)(seg + p) * Kdim + ((cb ^ (row & 7)) * 8);
    }
    // B staging: 2 slots/thread (128 rows x 8 cb)
    const float* bsrc[2]; int bdst[2];
    #pragma unroll
    for (int s = 0; s < 2; ++s) {
        int idx = s * 512 + tid;
        int r = idx >> 3, cb = idx & 7;
        bsrc[s] = Bd + (size_t)(h0 + r) * Kdim + cb * 8;
        bdst[s] = r * BK + ((cb ^ (r & 7)) * 8);
    }

    f32x4 zero; zero[0] = 0.f; zero[1] = 0.f; zero[2] = 0.f; zero[3] = 0.f;
    f32x4 acc[2][8];
    #pragma unroll
    for (int a = 0; a < 2; ++a)
        #pragma unroll
        for (int b = 0; b < 8; ++b) acc[a][b] = zero;

    auto issueA = [&](int k0, int pb) {
        #pragma unroll
        for (int s = 0; s < 4; ++s)
            gld_lds16(asrc[s] + k0, (u16*)As[pb] + (s * 8 + w) * 512);
    };
    auto mmaStep = [&](int pb) {
        #pragma unroll
        for (int ks = 0; ks < 2; ++ks) {
            short8 a[2];
            #pragma unroll
            for (int fm = 0; fm < 2; ++fm) {
                int row = w * 32 + fm * 16 + (lane & 15);
                int cb = ks * 4 + (lane >> 4);
                a[fm] = *(const short8*)((const u16*)As[pb] + row * BK + ((cb ^ (row & 7)) * 8));
            }
            #pragma unroll
            for (int fn = 0; fn < 8; ++fn) {
                int brow = fn * 16 + (lane & 15);
                int cb = ks * 4 + (lane >> 4);
                short8 b = *(const short8*)(&Bs[brow * BK + ((cb ^ (brow & 7)) * 8)]);
                acc[0][fn] = mfma16(a[0], b, acc[0][fn]);
                acc[1][fn] = mfma16(a[1], b, acc[1][fn]);
            }
        }
    };

    const int NK = Kdim / BK; // 22 or 44 (even)
    issueA(0, 0);
    float4 bA0[2], bA1[2], bB0[2], bB1[2];
    #pragma unroll
    for (int s = 0; s < 2; ++s) { bA0[s] = *(const float4*)bsrc[s]; bA1[s] = *(const float4*)(bsrc[s] + 4); }

    for (int ki = 0; ki < NK; ki += 2) {
        #pragma unroll
        for (int s = 0; s < 2; ++s)
            *(ushort8*)(&Bs[bdst[s]]) = cvt8(bA0[s], bA1[s]);
        if (ki + 1 < NK) {
            int k1 = (ki + 1) * BK;
            issueA(k1, 1);
            #pragma unroll
            for (int s = 0; s < 2; ++s) { bB0[s] = *(const float4*)(bsrc[s] + k1); bB1[s] = *(const float4*)(bsrc[s] + k1 + 4); }
        }
        __syncthreads();
        mmaStep(0);
        __syncthreads();
        if (ki + 1 < NK) {
            #pragma unroll
            for (int s = 0; s < 2; ++s)
                *(ushort8*)(&Bs[bdst[s]]) = cvt8(bB0[s], bB1[s]);
            if (ki + 2 < NK) {
                int k2 = (ki + 2) * BK;
                issueA(k2, 0);
                #pragma unroll
                for (int s = 0; s < 2; ++s) { bA0[s] = *(const float4*)(bsrc[s] + k2); bA1[s] = *(const float4*)(bsrc[s] + k2 + 4); }
            }
            __syncthreads();
            mmaStep(1);
            __syncthreads();
        }
    }

    int r0 = (lane >> 4) * 4, cc = lane & 15;
    #pragma unroll
    for (int fm = 0; fm < 2; ++fm) {
        #pragma unroll
        for (int r = 0; r < 4; ++r) {
            int p = m0 + w * 32 + fm * 16 + r0 + r;
            if (p < n) {
                int tok = tok_list ? tok_list[seg + p] : p;
                float wt = w_list ? w_list[seg + p] : 1.0f;
                size_t ob = (size_t)tok * H_DIM + h0 + cc;
                #pragma unroll
                for (int fn = 0; fn < 8; ++fn)
                    atomicAdd(&out[ob + fn * 16], acc[fm][fn][r] * wt);
            }
        }
    }
}

extern "C" void kernel_launch(void* const* d_in, const int* in_sizes, int n_in,
                              void* d_out, int out_size, void* d_ws, size_t ws_size,
                              hipStream_t stream) {
    const float* x         = (const float*)d_in[0];
    const float* gate_w    = (const float*)d_in[1];
    const float* e_bias    = (const float*)d_in[2];
    const float* gate_proj = (const float*)d_in[3];
    const float* up_proj   = (const float*)d_in[4];
    const float* down_proj = (const float*)d_in[5];
    const float* sgw       = (const float*)d_in[6];
    const float* suw       = (const float*)d_in[7];
    const float* sdw       = (const float*)d_in[8];
    float* out = (float*)d_out;

    char* ws = (char*)d_ws;
    size_t off = 0;
    auto alloc = [&](size_t bytes) -> char* {
        char* p = ws + off;
        off += (bytes + 255) & ~(size_t)255;
        return p;
    };
    float* logits   = (float*)alloc((size_t)T_TOK * 64 * 4);
    int*   topk_idx = (int*)  alloc((size_t)T_TOK * 8 * 4);
    float* topk_w   = (float*)alloc((size_t)T_TOK * 8 * 4);
    int*   counts   = (int*)  alloc(256);   // [64]
    int*   offsets  = (int*)  alloc(512);   // [65]
    int*   fill     = (int*)  alloc(256);   // [64]
    int*   tok_list = (int*)  alloc((size_t)T_TOK * 8 * 4);
    float* w_list   = (float*)alloc((size_t)T_TOK * 8 * 4);
    u16*   xb       = (u16*)  alloc((size_t)T_TOK * H_DIM * 2);
    u16*   inter    = (u16*)  alloc((size_t)T_TOK * 8 * I_DIM * 2); // reused for shared

    hipMemsetAsync(d_out, 0, (size_t)out_size * 4, stream);
    hipMemsetAsync(counts, 0, 1024, stream); // counts + offsets + fill

    k_cvt<<<(T_TOK * H_DIM) / 2048, 256, 0, stream>>>(x, xb);
    k_gate_logits<<<T_TOK / 8, 256, 0, stream>>>(x, gate_w, logits);
    k_topk<<<T_TOK / 256, 256, 0, stream>>>(logits, e_bias, topk_idx, topk_w, counts);
    k_prefix<<<1, 64, 0, stream>>>(counts, offsets);
    k_scatter<<<(T_TOK * 8) / 256, 256, 0, stream>>>(topk_idx, topk_w, offsets, fill, tok_list, w_list);

    // routed experts
    k_gateup<<<dim3(I_DIM / 64, T_TOK / BM, 64), 512, 0, stream>>>(
        xb, gate_proj, up_proj, offsets, tok_list, inter, I_DIM);
    k_down<<<dim3(H_DIM / 128, T_TOK / BM, 64), 512, 0, stream>>>(
        inter, I_DIM, down_proj, offsets, tok_list, w_list, out);

    // shared experts
    k_gateup<<<dim3(SI_DIM / 64, T_TOK / BM, 1), 512, 0, stream>>>(
        xb, sgw, suw, nullptr, nullptr, inter, SI_DIM);
    k_down<<<dim3(H_DIM / 128, T_TOK / BM, 1), 512, 0, stream>>>(
        inter, SI_DIM, sdw, nullptr, nullptr, nullptr, out);
}

// Round 3
// 1807.315 us; speedup vs baseline: 1.3500x; 1.3500x over previous
//
#include <hip/hip_runtime.h>

typedef unsigned short u16;
typedef unsigned int u32;
typedef __attribute__((ext_vector_type(8))) short short8;
typedef __attribute__((ext_vector_type(8))) u16 ushort8;
typedef __attribute__((ext_vector_type(4))) float f32x4;

#define T_TOK 2048
#define H_DIM 2048
#define NEXP 64
#define I_DIM 1408
#define SI_DIM 2816
#define BM 256
#define BK 64

__device__ __forceinline__ u16 f2bf(float f) {
    u32 u = __builtin_bit_cast(u32, f);
    u32 r = u + 0x7FFFu + ((u >> 16) & 1u);
    return (u16)(r >> 16);
}

__device__ __forceinline__ ushort8 cvt8(float4 a, float4 b) {
    ushort8 o;
    o[0] = f2bf(a.x); o[1] = f2bf(a.y); o[2] = f2bf(a.z); o[3] = f2bf(a.w);
    o[4] = f2bf(b.x); o[5] = f2bf(b.y); o[6] = f2bf(b.z); o[7] = f2bf(b.w);
    return o;
}

__device__ __forceinline__ ushort8 ldcvt(const float* p) {
    float4 a = *(const float4*)p;
    float4 b = *(const float4*)(p + 4);
    return cvt8(a, b);
}

__device__ __forceinline__ f32x4 mfma16(short8 a, short8 b, f32x4 c) {
    return __builtin_amdgcn_mfma_f32_16x16x32_bf16(a, b, c, 0, 0, 0);
}

__device__ __forceinline__ void gld_lds16(const void* g, void* l) {
    __builtin_amdgcn_global_load_lds(
        (const __attribute__((address_space(1))) void*)(g),
        (__attribute__((address_space(3))) void*)(l), 16, 0, 0);
}

// ---------------- x -> bf16 ----------------
__global__ __launch_bounds__(256) void k_cvt(const float* __restrict__ x, u16* __restrict__ xb) {
    int i = (blockIdx.x * 256 + threadIdx.x) * 8;
    float4 v0 = *(const float4*)(x + i);
    float4 v1 = *(const float4*)(x + i + 4);
    *(ushort8*)(xb + i) = cvt8(v0, v1);
}

// ---------------- gating logits: f64 accumulation ----------------
__global__ __launch_bounds__(256) void k_gate_logits(const float* __restrict__ x,
        const float* __restrict__ gw, float* __restrict__ logits) {
    __shared__ float xs[8][65];
    __shared__ float wsh[64][65];
    int tid = threadIdx.x;
    int t0 = blockIdx.x * 8;
    double acc0 = 0.0, acc1 = 0.0;
    int e = tid & 63, tg = tid >> 6; // tg in [0,4)
    for (int k0 = 0; k0 < H_DIM; k0 += 64) {
        #pragma unroll
        for (int s = 0; s < 2; ++s) {
            int idx = s * 256 + tid;
            int r = idx >> 6, k = idx & 63;
            xs[r][k] = x[(size_t)(t0 + r) * H_DIM + k0 + k];
        }
        #pragma unroll
        for (int s = 0; s < 16; ++s) {
            int idx = s * 256 + tid;
            int r = idx >> 6, k = idx & 63;
            wsh[r][k] = gw[(size_t)r * H_DIM + k0 + k];
        }
        __syncthreads();
        #pragma unroll 8
        for (int k = 0; k < 64; ++k) {
            double wv = (double)wsh[e][k];
            acc0 += (double)xs[tg][k] * wv;
            acc1 += (double)xs[tg + 4][k] * wv;
        }
        __syncthreads();
    }
    logits[(size_t)(t0 + tg) * NEXP + e] = (float)acc0;
    logits[(size_t)(t0 + tg + 4) * NEXP + e] = (float)acc1;
}

// ---------------- per-token group-restricted top-k ----------------
__global__ __launch_bounds__(256) void k_topk(const float* __restrict__ logits,
        const float* __restrict__ ebias, int* __restrict__ topk_idx,
        float* __restrict__ topk_w, int* __restrict__ counts) {
    __shared__ float bsh[64];
    if (threadIdx.x < 64) bsh[threadIdx.x] = ebias[threadIdx.x];
    __syncthreads();
    int t = blockIdx.x * 256 + threadIdx.x;
    float sc[64];
    #pragma unroll
    for (int e2 = 0; e2 < 64; ++e2) {
        float lg = logits[(size_t)t * 64 + e2];
        sc[e2] = 1.0f / (1.0f + expf(-lg));
    }
    float gsc[8];
    #pragma unroll
    for (int g = 0; g < 8; ++g) {
        float m1 = -1e30f, m2 = -1e30f;
        #pragma unroll
        for (int j = 0; j < 8; ++j) {
            float v = sc[g * 8 + j] + bsh[g * 8 + j];
            if (v > m1) { m2 = m1; m1 = v; }
            else if (v > m2) { m2 = v; }
        }
        gsc[g] = m1 + m2;
    }
    u32 gmask = 0;
    #pragma unroll
    for (int it = 0; it < 4; ++it) {
        float best = -1e30f; int bi = 0;
        #pragma unroll
        for (int g = 0; g < 8; ++g) {
            bool ok = !((gmask >> g) & 1u);
            if (ok && gsc[g] > best) { best = gsc[g]; bi = g; }
        }
        gmask |= 1u << bi;
    }
    unsigned long long avail = 0ull;
    #pragma unroll
    for (int g = 0; g < 8; ++g)
        if ((gmask >> g) & 1u) avail |= (0xFFull << (g * 8));
    float wsum = 0.f;
    int idx[8]; float wv[8];
    #pragma unroll
    for (int it = 0; it < 8; ++it) {
        float best = -1e30f, bw = 0.f; int bi = 0;
        #pragma unroll
        for (int e2 = 0; e2 < 64; ++e2) {
            bool ok = (avail >> e2) & 1ull;
            float v = sc[e2] + bsh[e2];
            if (ok && v > best) { best = v; bi = e2; bw = sc[e2]; }
        }
        avail &= ~(1ull << bi);
        idx[it] = bi; wv[it] = bw; wsum += bw;
    }
    float scale = 2.5f / (wsum + 1e-20f);
    #pragma unroll
    for (int it = 0; it < 8; ++it) {
        topk_idx[t * 8 + it] = idx[it];
        topk_w[t * 8 + it] = wv[it] * scale;
        atomicAdd(&counts[idx[it]], 1);
    }
}

// ---------------- prefix sum over 64 counts ----------------
__global__ void k_prefix(const int* __restrict__ counts, int* __restrict__ offsets) {
    if (threadIdx.x == 0) {
        int run = 0;
        for (int e = 0; e < 64; ++e) { offsets[e] = run; run += counts[e]; }
        offsets[64] = run;
    }
}

// ---------------- scatter (t,k) -> per-expert lists ----------------
__global__ __launch_bounds__(256) void k_scatter(const int* __restrict__ topk_idx,
        const float* __restrict__ topk_w, const int* __restrict__ offsets,
        int* __restrict__ fill, int* __restrict__ tok_list, float* __restrict__ w_list) {
    int gid = blockIdx.x * 256 + threadIdx.x;
    int t = gid >> 3;
    int e = topk_idx[gid];
    int pos = offsets[e] + atomicAdd(&fill[e], 1);
    tok_list[pos] = t;
    w_list[pos] = topk_w[gid];
}

// ---------------- fused gate+up+silu*mul grouped GEMM ----------------
// tile: 256 tokens x 64 I-rows, BK=64; 8 waves each 32m x 64n x {g,u}
// A via global_load_lds (source-preswizzled, dbuf), B cvt-at-load, staged 1 step ahead.
__global__ __launch_bounds__(512, 2) void k_gateup(
        const u16* __restrict__ xb,
        const float* __restrict__ gate_base, const float* __restrict__ up_base,
        const int* __restrict__ offsets, const int* __restrict__ tok_list,
        u16* __restrict__ inter, int Irows) {
    int i0 = blockIdx.x * 64;
    int m0 = blockIdx.y * BM;
    int e = blockIdx.z;
    int seg, n;
    if (offsets) { seg = offsets[e]; n = offsets[e + 1] - seg; }
    else { seg = 0; n = T_TOK; }
    if (m0 >= n) return;

    const float* Bg = gate_base + (size_t)e * Irows * H_DIM;
    const float* Bu = up_base + (size_t)e * Irows * H_DIM;

    __shared__ u16 As[2][BM * BK];   // 2 x 32KB, linear (source-preswizzled)
    __shared__ u16 Bsg[64 * BK];     // 8KB, xor-swizzled
    __shared__ u16 Bsu[64 * BK];     // 8KB

    int tid = threadIdx.x;
    int w = tid >> 6, lane = tid & 63;

    // A sources: 4 gld_lds calls/thread; call s covers LDS rows [(s*8+w)*8, +8)
    const u16* asrc[4];
    #pragma unroll
    for (int s = 0; s < 4; ++s) {
        int row = (s * 8 + w) * 8 + (lane >> 3);
        int cb = lane & 7;
        int p = m0 + row; if (p >= n) p = n - 1;
        int tok = tok_list ? tok_list[seg + p] : p;
        asrc[s] = xb + (size_t)tok * H_DIM + ((cb ^ (row & 7)) * 8);
    }
    // B staging: thread -> (row=tid>>3, cb=tid&7), one 16B slot per matrix
    int br = tid >> 3, bcb = tid & 7;
    const float* bgsrc = Bg + (size_t)(i0 + br) * H_DIM + bcb * 8;
    const float* busrc = Bu + (size_t)(i0 + br) * H_DIM + bcb * 8;
    int bdst = br * BK + ((bcb ^ (br & 7)) * 8);

    f32x4 zero; zero[0] = 0.f; zero[1] = 0.f; zero[2] = 0.f; zero[3] = 0.f;
    f32x4 accg[2][4], accu[2][4];
    #pragma unroll
    for (int a = 0; a < 2; ++a)
        #pragma unroll
        for (int b = 0; b < 4; ++b) { accg[a][b] = zero; accu[a][b] = zero; }

    auto issueA = [&](int k0, int pb) {
        #pragma unroll
        for (int s = 0; s < 4; ++s)
            gld_lds16(asrc[s] + k0, (u16*)As[pb] + (s * 8 + w) * 512);
    };
    auto mmaStep = [&](int pb) {
        #pragma unroll
        for (int ks = 0; ks < 2; ++ks) {
            short8 a[2];
            #pragma unroll
            for (int fm = 0; fm < 2; ++fm) {
                int row = w * 32 + fm * 16 + (lane & 15);
                int cb = ks * 4 + (lane >> 4);
                a[fm] = *(const short8*)((const u16*)As[pb] + row * BK + ((cb ^ (row & 7)) * 8));
            }
            #pragma unroll
            for (int fn = 0; fn < 4; ++fn) {
                int brow = fn * 16 + (lane & 15);
                int cb = ks * 4 + (lane >> 4);
                int boff = brow * BK + ((cb ^ (brow & 7)) * 8);
                short8 bg = *(const short8*)(&Bsg[boff]);
                short8 bu = *(const short8*)(&Bsu[boff]);
                accg[0][fn] = mfma16(a[0], bg, accg[0][fn]);
                accg[1][fn] = mfma16(a[1], bg, accg[1][fn]);
                accu[0][fn] = mfma16(a[0], bu, accu[0][fn]);
                accu[1][fn] = mfma16(a[1], bu, accu[1][fn]);
            }
        }
    };

    const int NK = H_DIM / BK; // 32 (even)
    // prologue: cvt at load -> ushort8 (4 VGPR each) instead of float4 pairs
    issueA(0, 0);
    ushort8 gA = ldcvt(bgsrc), uA = ldcvt(busrc);
    ushort8 gB, uB;

    for (int ki = 0; ki < NK; ki += 2) {
        // even step (buffer 0, regs A)
        *(ushort8*)(&Bsg[bdst]) = gA;
        *(ushort8*)(&Bsu[bdst]) = uA;
        if (ki + 1 < NK) {
            int k1 = (ki + 1) * BK;
            issueA(k1, 1);
            gB = ldcvt(bgsrc + k1); uB = ldcvt(busrc + k1);
        }
        __syncthreads();
        mmaStep(0);
        __syncthreads();
        // odd step (buffer 1, regs B)
        if (ki + 1 < NK) {
            *(ushort8*)(&Bsg[bdst]) = gB;
            *(ushort8*)(&Bsu[bdst]) = uB;
            if (ki + 2 < NK) {
                int k2 = (ki + 2) * BK;
                issueA(k2, 0);
                gA = ldcvt(bgsrc + k2); uA = ldcvt(busrc + k2);
            }
            __syncthreads();
            mmaStep(1);
            __syncthreads();
        }
    }

    int r0 = (lane >> 4) * 4, cc = lane & 15;
    #pragma unroll
    for (int fm = 0; fm < 2; ++fm) {
        #pragma unroll
        for (int r = 0; r < 4; ++r) {
            int p = m0 + w * 32 + fm * 16 + r0 + r;
            if (p < n) {
                size_t rowb = (size_t)(seg + p) * Irows + i0;
                #pragma unroll
                for (int fn = 0; fn < 4; ++fn) {
                    float g = accg[fm][fn][r], u = accu[fm][fn][r];
                    float val = g / (1.0f + expf(-g)) * u;
                    inter[rowb + fn * 16 + cc] = f2bf(val);
                }
            }
        }
    }
}

// ---------------- down-proj grouped GEMM, weighted atomic scatter ----------------
// tile: 256 rows x 128 H; BK=64; 8 waves each 32m x 128n
__global__ __launch_bounds__(512, 2) void k_down(
        const u16* __restrict__ inter, int Kdim,
        const float* __restrict__ down_base,
        const int* __restrict__ offsets, const int* __restrict__ tok_list,
        const float* __restrict__ w_list,
        float* __restrict__ out) {
    int h0 = blockIdx.x * 128;
    int m0 = blockIdx.y * BM;
    int e = blockIdx.z;
    int seg, n;
    if (offsets) { seg = offsets[e]; n = offsets[e + 1] - seg; }
    else { seg = 0; n = T_TOK; }
    if (m0 >= n) return;

    const float* Bd = down_base + (size_t)e * H_DIM * Kdim;

    __shared__ u16 As[2][BM * BK];   // 2 x 32KB
    __shared__ u16 Bs[128 * BK];     // 16KB, xor-swizzled

    int tid = threadIdx.x;
    int w = tid >> 6, lane = tid & 63;

    const u16* asrc[4];
    #pragma unroll
    for (int s = 0; s < 4; ++s) {
        int row = (s * 8 + w) * 8 + (lane >> 3);
        int cb = lane & 7;
        int p = m0 + row; if (p >= n) p = n - 1;
        asrc[s] = inter + (size_t)(seg + p) * Kdim + ((cb ^ (row & 7)) * 8);
    }
    // B staging: 2 slots/thread (128 rows x 8 cb)
    const float* bsrc[2]; int bdst[2];
    #pragma unroll
    for (int s = 0; s < 2; ++s) {
        int idx = s * 512 + tid;
        int r = idx >> 3, cb = idx & 7;
        bsrc[s] = Bd + (size_t)(h0 + r) * Kdim + cb * 8;
        bdst[s] = r * BK + ((cb ^ (r & 7)) * 8);
    }

    f32x4 zero; zero[0] = 0.f; zero[1] = 0.f; zero[2] = 0.f; zero[3] = 0.f;
    f32x4 acc[2][8];
    #pragma unroll
    for (int a = 0; a < 2; ++a)
        #pragma unroll
        for (int b = 0; b < 8; ++b) acc[a][b] = zero;

    auto issueA = [&](int k0, int pb) {
        #pragma unroll
        for (int s = 0; s < 4; ++s)
            gld_lds16(asrc[s] + k0, (u16*)As[pb] + (s * 8 + w) * 512);
    };
    auto mmaStep = [&](int pb) {
        #pragma unroll
        for (int ks = 0; ks < 2; ++ks) {
            short8 a[2];
            #pragma unroll
            for (int fm = 0; fm < 2; ++fm) {
                int row = w * 32 + fm * 16 + (lane & 15);
                int cb = ks * 4 + (lane >> 4);
                a[fm] = *(const short8*)((const u16*)As[pb] + row * BK + ((cb ^ (row & 7)) * 8));
            }
            #pragma unroll
            for (int fn = 0; fn < 8; ++fn) {
                int brow = fn * 16 + (lane & 15);
                int cb = ks * 4 + (lane >> 4);
                short8 b = *(const short8*)(&Bs[brow * BK + ((cb ^ (brow & 7)) * 8)]);
                acc[0][fn] = mfma16(a[0], b, acc[0][fn]);
                acc[1][fn] = mfma16(a[1], b, acc[1][fn]);
            }
        }
    };

    const int NK = Kdim / BK; // 22 or 44 (even)
    issueA(0, 0);
    ushort8 sA[2], sB[2];
    #pragma unroll
    for (int s = 0; s < 2; ++s) sA[s] = ldcvt(bsrc[s]);

    for (int ki = 0; ki < NK; ki += 2) {
        #pragma unroll
        for (int s = 0; s < 2; ++s)
            *(ushort8*)(&Bs[bdst[s]]) = sA[s];
        if (ki + 1 < NK) {
            int k1 = (ki + 1) * BK;
            issueA(k1, 1);
            #pragma unroll
            for (int s = 0; s < 2; ++s) sB[s] = ldcvt(bsrc[s] + k1);
        }
        __syncthreads();
        mmaStep(0);
        __syncthreads();
        if (ki + 1 < NK) {
            #pragma unroll
            for (int s = 0; s < 2; ++s)
                *(ushort8*)(&Bs[bdst[s]]) = sB[s];
            if (ki + 2 < NK) {
                int k2 = (ki + 2) * BK;
                issueA(k2, 0);
                #pragma unroll
                for (int s = 0; s < 2; ++s) sA[s] = ldcvt(bsrc[s] + k2);
            }
            __syncthreads();
            mmaStep(1);
            __syncthreads();
        }
    }

    int r0 = (lane >> 4) * 4, cc = lane & 15;
    #pragma unroll
    for (int fm = 0; fm < 2; ++fm) {
        #pragma unroll
        for (int r = 0; r < 4; ++r) {
            int p = m0 + w * 32 + fm * 16 + r0 + r;
            if (p < n) {
                int tok = tok_list ? tok_list[seg + p] : p;
                float wt = w_list ? w_list[seg + p] : 1.0f;
                size_t ob = (size_t)tok * H_DIM + h0 + cc;
                #pragma unroll
                for (int fn = 0; fn < 8; ++fn)
                    atomicAdd(&out[ob + fn * 16], acc[fm][fn][r] * wt);
            }
        }
    }
}

extern "C" void kernel_launch(void* const* d_in, const int* in_sizes, int n_in,
                              void* d_out, int out_size, void* d_ws, size_t ws_size,
                              hipStream_t stream) {
    const float* x         = (const float*)d_in[0];
    const float* gate_w    = (const float*)d_in[1];
    const float* e_bias    = (const float*)d_in[2];
    const float* gate_proj = (const float*)d_in[3];
    const float* up_proj   = (const float*)d_in[4];
    const float* down_proj = (const float*)d_in[5];
    const float* sgw       = (const float*)d_in[6];
    const float* suw       = (const float*)d_in[7];
    const float* sdw       = (const float*)d_in[8];
    float* out = (float*)d_out;

    char* ws = (char*)d_ws;
    size_t off = 0;
    auto alloc = [&](size_t bytes) -> char* {
        char* p = ws + off;
        off += (bytes + 255) & ~(size_t)255;
        return p;
    };
    float* logits   = (float*)alloc((size_t)T_TOK * 64 * 4);
    int*   topk_idx = (int*)  alloc((size_t)T_TOK * 8 * 4);
    float* topk_w   = (float*)alloc((size_t)T_TOK * 8 * 4);
    int*   counts   = (int*)  alloc(256);   // [64]
    int*   offsets  = (int*)  alloc(512);   // [65]
    int*   fill     = (int*)  alloc(256);   // [64]
    int*   tok_list = (int*)  alloc((size_t)T_TOK * 8 * 4);
    float* w_list   = (float*)alloc((size_t)T_TOK * 8 * 4);
    u16*   xb       = (u16*)  alloc((size_t)T_TOK * H_DIM * 2);
    u16*   inter    = (u16*)  alloc((size_t)T_TOK * 8 * I_DIM * 2); // reused for shared

    hipMemsetAsync(d_out, 0, (size_t)out_size * 4, stream);
    hipMemsetAsync(counts, 0, 1024, stream); // counts + offsets + fill

    k_cvt<<<(T_TOK * H_DIM) / 2048, 256, 0, stream>>>(x, xb);
    k_gate_logits<<<T_TOK / 8, 256, 0, stream>>>(x, gate_w, logits);
    k_topk<<<T_TOK / 256, 256, 0, stream>>>(logits, e_bias, topk_idx, topk_w, counts);
    k_prefix<<<1, 64, 0, stream>>>(counts, offsets);
    k_scatter<<<(T_TOK * 8) / 256, 256, 0, stream>>>(topk_idx, topk_w, offsets, fill, tok_list, w_list);

    // routed experts
    k_gateup<<<dim3(I_DIM / 64, T_TOK / BM, 64), 512, 0, stream>>>(
        xb, gate_proj, up_proj, offsets, tok_list, inter, I_DIM);
    k_down<<<dim3(H_DIM / 128, T_TOK / BM, 64), 512, 0, stream>>>(
        inter, I_DIM, down_proj, offsets, tok_list, w_list, out);

    // shared experts
    k_gateup<<<dim3(SI_DIM / 64, T_TOK / BM, 1), 512, 0, stream>>>(
        xb, sgw, suw, nullptr, nullptr, inter, SI_DIM);
    k_down<<<dim3(H_DIM / 128, T_TOK / BM, 1), 512, 0, stream>>>(
        inter, SI_DIM, sdw, nullptr, nullptr, nullptr, out);
}

// Round 4
// 1597.637 us; speedup vs baseline: 1.5271x; 1.1312x over previous
//
#include <hip/hip_runtime.h>

typedef unsigned short u16;
typedef unsigned int u32;
typedef __attribute__((ext_vector_type(8))) short short8;
typedef __attribute__((ext_vector_type(8))) u16 ushort8;
typedef __attribute__((ext_vector_type(4))) float f32x4;

#define T_TOK 2048
#define H_DIM 2048
#define NEXP 64
#define I_DIM 1408
#define SI_DIM 2816
#define BM 256
#define BK 64

__device__ __forceinline__ u16 f2bf(float f) {
    u32 u = __builtin_bit_cast(u32, f);
    u32 r = u + 0x7FFFu + ((u >> 16) & 1u);
    return (u16)(r >> 16);
}

__device__ __forceinline__ ushort8 cvt8(float4 a, float4 b) {
    ushort8 o;
    o[0] = f2bf(a.x); o[1] = f2bf(a.y); o[2] = f2bf(a.z); o[3] = f2bf(a.w);
    o[4] = f2bf(b.x); o[5] = f2bf(b.y); o[6] = f2bf(b.z); o[7] = f2bf(b.w);
    return o;
}

__device__ __forceinline__ f32x4 mfma16(short8 a, short8 b, f32x4 c) {
    return __builtin_amdgcn_mfma_f32_16x16x32_bf16(a, b, c, 0, 0, 0);
}

__device__ __forceinline__ void gld_lds16(const void* g, void* l) {
    __builtin_amdgcn_global_load_lds(
        (const __attribute__((address_space(1))) void*)(g),
        (__attribute__((address_space(3))) void*)(l), 16, 0, 0);
}

#define WAIT_VM8()  { asm volatile("s_waitcnt vmcnt(8)" ::: "memory"); __builtin_amdgcn_sched_barrier(0); }
#define WAIT_LGKM() { asm volatile("s_waitcnt lgkmcnt(0)" ::: "memory"); __builtin_amdgcn_sched_barrier(0); }
#define BAR()       { __builtin_amdgcn_s_barrier(); __builtin_amdgcn_sched_barrier(0); }

// ---------------- x -> bf16 ----------------
__global__ __launch_bounds__(256) void k_cvt(const float* __restrict__ x, u16* __restrict__ xb) {
    int i = (blockIdx.x * 256 + threadIdx.x) * 8;
    float4 v0 = *(const float4*)(x + i);
    float4 v1 = *(const float4*)(x + i + 4);
    *(ushort8*)(xb + i) = cvt8(v0, v1);
}

// ---------------- gating logits: f64 accumulation ----------------
__global__ __launch_bounds__(256) void k_gate_logits(const float* __restrict__ x,
        const float* __restrict__ gw, float* __restrict__ logits) {
    __shared__ float xs[8][65];
    __shared__ float wsh[64][65];
    int tid = threadIdx.x;
    int t0 = blockIdx.x * 8;
    double acc0 = 0.0, acc1 = 0.0;
    int e = tid & 63, tg = tid >> 6; // tg in [0,4)
    for (int k0 = 0; k0 < H_DIM; k0 += 64) {
        #pragma unroll
        for (int s = 0; s < 2; ++s) {
            int idx = s * 256 + tid;
            int r = idx >> 6, k = idx & 63;
            xs[r][k] = x[(size_t)(t0 + r) * H_DIM + k0 + k];
        }
        #pragma unroll
        for (int s = 0; s < 16; ++s) {
            int idx = s * 256 + tid;
            int r = idx >> 6, k = idx & 63;
            wsh[r][k] = gw[(size_t)r * H_DIM + k0 + k];
        }
        __syncthreads();
        #pragma unroll 8
        for (int k = 0; k < 64; ++k) {
            double wv = (double)wsh[e][k];
            acc0 += (double)xs[tg][k] * wv;
            acc1 += (double)xs[tg + 4][k] * wv;
        }
        __syncthreads();
    }
    logits[(size_t)(t0 + tg) * NEXP + e] = (float)acc0;
    logits[(size_t)(t0 + tg + 4) * NEXP + e] = (float)acc1;
}

// ---------------- per-token group-restricted top-k ----------------
__global__ __launch_bounds__(256) void k_topk(const float* __restrict__ logits,
        const float* __restrict__ ebias, int* __restrict__ topk_idx,
        float* __restrict__ topk_w, int* __restrict__ counts) {
    __shared__ float bsh[64];
    if (threadIdx.x < 64) bsh[threadIdx.x] = ebias[threadIdx.x];
    __syncthreads();
    int t = blockIdx.x * 256 + threadIdx.x;
    float sc[64];
    #pragma unroll
    for (int e2 = 0; e2 < 64; ++e2) {
        float lg = logits[(size_t)t * 64 + e2];
        sc[e2] = 1.0f / (1.0f + expf(-lg));
    }
    float gsc[8];
    #pragma unroll
    for (int g = 0; g < 8; ++g) {
        float m1 = -1e30f, m2 = -1e30f;
        #pragma unroll
        for (int j = 0; j < 8; ++j) {
            float v = sc[g * 8 + j] + bsh[g * 8 + j];
            if (v > m1) { m2 = m1; m1 = v; }
            else if (v > m2) { m2 = v; }
        }
        gsc[g] = m1 + m2;
    }
    u32 gmask = 0;
    #pragma unroll
    for (int it = 0; it < 4; ++it) {
        float best = -1e30f; int bi = 0;
        #pragma unroll
        for (int g = 0; g < 8; ++g) {
            bool ok = !((gmask >> g) & 1u);
            if (ok && gsc[g] > best) { best = gsc[g]; bi = g; }
        }
        gmask |= 1u << bi;
    }
    unsigned long long avail = 0ull;
    #pragma unroll
    for (int g = 0; g < 8; ++g)
        if ((gmask >> g) & 1u) avail |= (0xFFull << (g * 8));
    float wsum = 0.f;
    int idx[8]; float wv[8];
    #pragma unroll
    for (int it = 0; it < 8; ++it) {
        float best = -1e30f, bw = 0.f; int bi = 0;
        #pragma unroll
        for (int e2 = 0; e2 < 64; ++e2) {
            bool ok = (avail >> e2) & 1ull;
            float v = sc[e2] + bsh[e2];
            if (ok && v > best) { best = v; bi = e2; bw = sc[e2]; }
        }
        avail &= ~(1ull << bi);
        idx[it] = bi; wv[it] = bw; wsum += bw;
    }
    float scale = 2.5f / (wsum + 1e-20f);
    #pragma unroll
    for (int it = 0; it < 8; ++it) {
        topk_idx[t * 8 + it] = idx[it];
        topk_w[t * 8 + it] = wv[it] * scale;
        atomicAdd(&counts[idx[it]], 1);
    }
}

// ---------------- prefix sum over 64 counts ----------------
__global__ void k_prefix(const int* __restrict__ counts, int* __restrict__ offsets) {
    if (threadIdx.x == 0) {
        int run = 0;
        for (int e = 0; e < 64; ++e) { offsets[e] = run; run += counts[e]; }
        offsets[64] = run;
    }
}

// ---------------- scatter (t,k) -> per-expert lists ----------------
__global__ __launch_bounds__(256) void k_scatter(const int* __restrict__ topk_idx,
        const float* __restrict__ topk_w, const int* __restrict__ offsets,
        int* __restrict__ fill, int* __restrict__ tok_list, float* __restrict__ w_list) {
    int gid = blockIdx.x * 256 + threadIdx.x;
    int t = gid >> 3;
    int e = topk_idx[gid];
    int pos = offsets[e] + atomicAdd(&fill[e], 1);
    tok_list[pos] = t;
    w_list[pos] = topk_w[gid];
}

// ---------------- fused gate+up+silu*mul grouped GEMM ----------------
// 256m x 64n, BK=64, 8 waves. Counted-vmcnt depth-2 pipeline:
// per iter issue exactly 8 vmem loads (4 gld_lds A + 4 float4 B), wait vmcnt(8).
__global__ __launch_bounds__(512, 2) void k_gateup(
        const u16* __restrict__ xb,
        const float* __restrict__ gate_base, const float* __restrict__ up_base,
        const int* __restrict__ offsets, const int* __restrict__ tok_list,
        u16* __restrict__ inter, int Irows) {
    int i0 = blockIdx.x * 64;
    int m0 = blockIdx.y * BM;
    int e = blockIdx.z;
    int seg, n;
    if (offsets) { seg = offsets[e]; n = offsets[e + 1] - seg; }
    else { seg = 0; n = T_TOK; }
    if (m0 >= n) return;

    const float* Bg = gate_base + (size_t)e * Irows * H_DIM;
    const float* Bu = up_base + (size_t)e * Irows * H_DIM;

    __shared__ u16 As[2][BM * BK];   // 2 x 32KB, linear (source-preswizzled)
    __shared__ u16 Bsg[64 * BK];     // 8KB, xor-swizzled
    __shared__ u16 Bsu[64 * BK];     // 8KB

    int tid = threadIdx.x;
    int w = tid >> 6, lane = tid & 63;

    const u16* asrc[4];
    #pragma unroll
    for (int s = 0; s < 4; ++s) {
        int row = (s * 8 + w) * 8 + (lane >> 3);
        int cb = lane & 7;
        int p = m0 + row; if (p >= n) p = n - 1;
        int tok = tok_list ? tok_list[seg + p] : p;
        asrc[s] = xb + (size_t)tok * H_DIM + ((cb ^ (row & 7)) * 8);
    }
    int br = tid >> 3, bcb = tid & 7;
    const float* bgsrc = Bg + (size_t)(i0 + br) * H_DIM + bcb * 8;
    const float* busrc = Bu + (size_t)(i0 + br) * H_DIM + bcb * 8;
    int bdst = br * BK + ((bcb ^ (br & 7)) * 8);

    f32x4 zero; zero[0] = 0.f; zero[1] = 0.f; zero[2] = 0.f; zero[3] = 0.f;
    f32x4 accg[2][4], accu[2][4];
    #pragma unroll
    for (int a = 0; a < 2; ++a)
        #pragma unroll
        for (int b = 0; b < 4; ++b) { accg[a][b] = zero; accu[a][b] = zero; }

    auto issueA = [&](int k0, int pb) {
        #pragma unroll
        for (int s = 0; s < 4; ++s)
            gld_lds16(asrc[s] + k0, (u16*)As[pb] + (s * 8 + w) * 512);
    };
    auto mmaStep = [&](int pb) {
        #pragma unroll
        for (int ks = 0; ks < 2; ++ks) {
            short8 a[2];
            #pragma unroll
            for (int fm = 0; fm < 2; ++fm) {
                int row = w * 32 + fm * 16 + (lane & 15);
                int cb = ks * 4 + (lane >> 4);
                a[fm] = *(const short8*)((const u16*)As[pb] + row * BK + ((cb ^ (row & 7)) * 8));
            }
            #pragma unroll
            for (int fn = 0; fn < 4; ++fn) {
                int brow = fn * 16 + (lane & 15);
                int cb = ks * 4 + (lane >> 4);
                int boff = brow * BK + ((cb ^ (brow & 7)) * 8);
                short8 bg = *(const short8*)(&Bsg[boff]);
                short8 bu = *(const short8*)(&Bsu[boff]);
                accg[0][fn] = mfma16(a[0], bg, accg[0][fn]);
                accg[1][fn] = mfma16(a[1], bg, accg[1][fn]);
                accu[0][fn] = mfma16(a[0], bu, accu[0][fn]);
                accu[1][fn] = mfma16(a[1], bu, accu[1][fn]);
            }
        }
    };

    const int NK = H_DIM / BK; // 32, even
    // prologue: tiles 0 and 1 in flight (16 loads)
    issueA(0, 0);
    float4 gA0 = *(const float4*)bgsrc,        gA1 = *(const float4*)(bgsrc + 4);
    float4 uA0 = *(const float4*)busrc,        uA1 = *(const float4*)(busrc + 4);
    issueA(BK, 1);
    float4 gB0 = *(const float4*)(bgsrc + BK), gB1 = *(const float4*)(bgsrc + BK + 4);
    float4 uB0 = *(const float4*)(busrc + BK), uB1 = *(const float4*)(busrc + BK + 4);
    __builtin_amdgcn_sched_barrier(0);

    for (int t = 0; t < NK; t += 2) {
        // ---- even step: buf0, reg set A ----
        WAIT_VM8();                       // tile t complete; tile t+1 in flight
        *(ushort8*)(&Bsg[bdst]) = cvt8(gA0, gA1);
        *(ushort8*)(&Bsu[bdst]) = cvt8(uA0, uA1);
        WAIT_LGKM();
        BAR();
        mmaStep(0);
        __builtin_amdgcn_sched_barrier(0);
        BAR();
        if (t + 2 < NK) {                 // issue tile t+2 into buf0 / set A
            int k2 = (t + 2) * BK;
            issueA(k2, 0);
            gA0 = *(const float4*)(bgsrc + k2); gA1 = *(const float4*)(bgsrc + k2 + 4);
            uA0 = *(const float4*)(busrc + k2); uA1 = *(const float4*)(busrc + k2 + 4);
        }
        __builtin_amdgcn_sched_barrier(0);
        // ---- odd step: buf1, reg set B ----
        WAIT_VM8();                       // tile t+1 complete; tile t+2 in flight
        *(ushort8*)(&Bsg[bdst]) = cvt8(gB0, gB1);
        *(ushort8*)(&Bsu[bdst]) = cvt8(uB0, uB1);
        WAIT_LGKM();
        BAR();
        mmaStep(1);
        __builtin_amdgcn_sched_barrier(0);
        BAR();
        if (t + 3 < NK) {                 // issue tile t+3 into buf1 / set B
            int k3 = (t + 3) * BK;
            issueA(k3, 1);
            gB0 = *(const float4*)(bgsrc + k3); gB1 = *(const float4*)(bgsrc + k3 + 4);
            uB0 = *(const float4*)(busrc + k3); uB1 = *(const float4*)(busrc + k3 + 4);
        }
        __builtin_amdgcn_sched_barrier(0);
    }

    int r0 = (lane >> 4) * 4, cc = lane & 15;
    #pragma unroll
    for (int fm = 0; fm < 2; ++fm) {
        #pragma unroll
        for (int r = 0; r < 4; ++r) {
            int p = m0 + w * 32 + fm * 16 + r0 + r;
            if (p < n) {
                size_t rowb = (size_t)(seg + p) * Irows + i0;
                #pragma unroll
                for (int fn = 0; fn < 4; ++fn) {
                    float g = accg[fm][fn][r], u = accu[fm][fn][r];
                    float val = g / (1.0f + expf(-g)) * u;
                    inter[rowb + fn * 16 + cc] = f2bf(val);
                }
            }
        }
    }
}

// ---------------- down-proj grouped GEMM, weighted atomic scatter ----------------
// 256m x 128n, BK=64, 8 waves. Same counted-vmcnt depth-2 pipeline.
__global__ __launch_bounds__(512, 2) void k_down(
        const u16* __restrict__ inter, int Kdim,
        const float* __restrict__ down_base,
        const int* __restrict__ offsets, const int* __restrict__ tok_list,
        const float* __restrict__ w_list,
        float* __restrict__ out) {
    int h0 = blockIdx.x * 128;
    int m0 = blockIdx.y * BM;
    int e = blockIdx.z;
    int seg, n;
    if (offsets) { seg = offsets[e]; n = offsets[e + 1] - seg; }
    else { seg = 0; n = T_TOK; }
    if (m0 >= n) return;

    const float* Bd = down_base + (size_t)e * H_DIM * Kdim;

    __shared__ u16 As[2][BM * BK];   // 2 x 32KB
    __shared__ u16 Bs[128 * BK];     // 16KB, xor-swizzled

    int tid = threadIdx.x;
    int w = tid >> 6, lane = tid & 63;

    const u16* asrc[4];
    #pragma unroll
    for (int s = 0; s < 4; ++s) {
        int row = (s * 8 + w) * 8 + (lane >> 3);
        int cb = lane & 7;
        int p = m0 + row; if (p >= n) p = n - 1;
        asrc[s] = inter + (size_t)(seg + p) * Kdim + ((cb ^ (row & 7)) * 8);
    }
    const float* bsrc[2]; int bdst[2];
    #pragma unroll
    for (int s = 0; s < 2; ++s) {
        int idx = s * 512 + tid;
        int r = idx >> 3, cb = idx & 7;
        bsrc[s] = Bd + (size_t)(h0 + r) * Kdim + cb * 8;
        bdst[s] = r * BK + ((cb ^ (r & 7)) * 8);
    }

    f32x4 zero; zero[0] = 0.f; zero[1] = 0.f; zero[2] = 0.f; zero[3] = 0.f;
    f32x4 acc[2][8];
    #pragma unroll
    for (int a = 0; a < 2; ++a)
        #pragma unroll
        for (int b = 0; b < 8; ++b) acc[a][b] = zero;

    auto issueA = [&](int k0, int pb) {
        #pragma unroll
        for (int s = 0; s < 4; ++s)
            gld_lds16(asrc[s] + k0, (u16*)As[pb] + (s * 8 + w) * 512);
    };
    auto mmaStep = [&](int pb) {
        #pragma unroll
        for (int ks = 0; ks < 2; ++ks) {
            short8 a[2];
            #pragma unroll
            for (int fm = 0; fm < 2; ++fm) {
                int row = w * 32 + fm * 16 + (lane & 15);
                int cb = ks * 4 + (lane >> 4);
                a[fm] = *(const short8*)((const u16*)As[pb] + row * BK + ((cb ^ (row & 7)) * 8));
            }
            #pragma unroll
            for (int fn = 0; fn < 8; ++fn) {
                int brow = fn * 16 + (lane & 15);
                int cb = ks * 4 + (lane >> 4);
                short8 b = *(const short8*)(&Bs[brow * BK + ((cb ^ (brow & 7)) * 8)]);
                acc[0][fn] = mfma16(a[0], b, acc[0][fn]);
                acc[1][fn] = mfma16(a[1], b, acc[1][fn]);
            }
        }
    };

    const int NK = Kdim / BK; // 22 or 44, even
    issueA(0, 0);
    float4 pA0 = *(const float4*)bsrc[0],        pA1 = *(const float4*)(bsrc[0] + 4);
    float4 qA0 = *(const float4*)bsrc[1],        qA1 = *(const float4*)(bsrc[1] + 4);
    issueA(BK, 1);
    float4 pB0 = *(const float4*)(bsrc[0] + BK), pB1 = *(const float4*)(bsrc[0] + BK + 4);
    float4 qB0 = *(const float4*)(bsrc[1] + BK), qB1 = *(const float4*)(bsrc[1] + BK + 4);
    __builtin_amdgcn_sched_barrier(0);

    for (int t = 0; t < NK; t += 2) {
        // ---- even step ----
        WAIT_VM8();
        *(ushort8*)(&Bs[bdst[0]]) = cvt8(pA0, pA1);
        *(ushort8*)(&Bs[bdst[1]]) = cvt8(qA0, qA1);
        WAIT_LGKM();
        BAR();
        mmaStep(0);
        __builtin_amdgcn_sched_barrier(0);
        BAR();
        if (t + 2 < NK) {
            int k2 = (t + 2) * BK;
            issueA(k2, 0);
            pA0 = *(const float4*)(bsrc[0] + k2); pA1 = *(const float4*)(bsrc[0] + k2 + 4);
            qA0 = *(const float4*)(bsrc[1] + k2); qA1 = *(const float4*)(bsrc[1] + k2 + 4);
        }
        __builtin_amdgcn_sched_barrier(0);
        // ---- odd step ----
        WAIT_VM8();
        *(ushort8*)(&Bs[bdst[0]]) = cvt8(pB0, pB1);
        *(ushort8*)(&Bs[bdst[1]]) = cvt8(qB0, qB1);
        WAIT_LGKM();
        BAR();
        mmaStep(1);
        __builtin_amdgcn_sched_barrier(0);
        BAR();
        if (t + 3 < NK) {
            int k3 = (t + 3) * BK;
            issueA(k3, 1);
            pB0 = *(const float4*)(bsrc[0] + k3); pB1 = *(const float4*)(bsrc[0] + k3 + 4);
            qB0 = *(const float4*)(bsrc[1] + k3); qB1 = *(const float4*)(bsrc[1] + k3 + 4);
        }
        __builtin_amdgcn_sched_barrier(0);
    }

    int r0 = (lane >> 4) * 4, cc = lane & 15;
    #pragma unroll
    for (int fm = 0; fm < 2; ++fm) {
        #pragma unroll
        for (int r = 0; r < 4; ++r) {
            int p = m0 + w * 32 + fm * 16 + r0 + r;
            if (p < n) {
                int tok = tok_list ? tok_list[seg + p] : p;
                float wt = w_list ? w_list[seg + p] : 1.0f;
                size_t ob = (size_t)tok * H_DIM + h0 + cc;
                #pragma unroll
                for (int fn = 0; fn < 8; ++fn)
                    atomicAdd(&out[ob + fn * 16], acc[fm][fn][r] * wt);
            }
        }
    }
}

extern "C" void kernel_launch(void* const* d_in, const int* in_sizes, int n_in,
                              void* d_out, int out_size, void* d_ws, size_t ws_size,
                              hipStream_t stream) {
    const float* x         = (const float*)d_in[0];
    const float* gate_w    = (const float*)d_in[1];
    const float* e_bias    = (const float*)d_in[2];
    const float* gate_proj = (const float*)d_in[3];
    const float* up_proj   = (const float*)d_in[4];
    const float* down_proj = (const float*)d_in[5];
    const float* sgw       = (const float*)d_in[6];
    const float* suw       = (const float*)d_in[7];
    const float* sdw       = (const float*)d_in[8];
    float* out = (float*)d_out;

    char* ws = (char*)d_ws;
    size_t off = 0;
    auto alloc = [&](size_t bytes) -> char* {
        char* p = ws + off;
        off += (bytes + 255) & ~(size_t)255;
        return p;
    };
    float* logits   = (float*)alloc((size_t)T_TOK * 64 * 4);
    int*   topk_idx = (int*)  alloc((size_t)T_TOK * 8 * 4);
    float* topk_w   = (float*)alloc((size_t)T_TOK * 8 * 4);
    int*   counts   = (int*)  alloc(256);   // [64]
    int*   offsets  = (int*)  alloc(512);   // [65]
    int*   fill     = (int*)  alloc(256);   // [64]
    int*   tok_list = (int*)  alloc((size_t)T_TOK * 8 * 4);
    float* w_list   = (float*)alloc((size_t)T_TOK * 8 * 4);
    u16*   xb       = (u16*)  alloc((size_t)T_TOK * H_DIM * 2);
    u16*   inter    = (u16*)  alloc((size_t)T_TOK * 8 * I_DIM * 2); // reused for shared

    hipMemsetAsync(d_out, 0, (size_t)out_size * 4, stream);
    hipMemsetAsync(counts, 0, 1024, stream); // counts + offsets + fill

    k_cvt<<<(T_TOK * H_DIM) / 2048, 256, 0, stream>>>(x, xb);
    k_gate_logits<<<T_TOK / 8, 256, 0, stream>>>(x, gate_w, logits);
    k_topk<<<T_TOK / 256, 256, 0, stream>>>(logits, e_bias, topk_idx, topk_w, counts);
    k_prefix<<<1, 64, 0, stream>>>(counts, offsets);
    k_scatter<<<(T_TOK * 8) / 256, 256, 0, stream>>>(topk_idx, topk_w, offsets, fill, tok_list, w_list);

    // routed experts
    k_gateup<<<dim3(I_DIM / 64, T_TOK / BM, 64), 512, 0, stream>>>(
        xb, gate_proj, up_proj, offsets, tok_list, inter, I_DIM);
    k_down<<<dim3(H_DIM / 128, T_TOK / BM, 64), 512, 0, stream>>>(
        inter, I_DIM, down_proj, offsets, tok_list, w_list, out);

    // shared experts
    k_gateup<<<dim3(SI_DIM / 64, T_TOK / BM, 1), 512, 0, stream>>>(
        xb, sgw, suw, nullptr, nullptr, inter, SI_DIM);
    k_down<<<dim3(H_DIM / 128, T_TOK / BM, 1), 512, 0, stream>>>(
        inter, SI_DIM, sdw, nullptr, nullptr, nullptr, out);
}